// Round 21
// baseline (461.310 us; speedup 1.0000x reference)
//
#include <hip/hip_runtime.h>
#include <hip/hip_cooperative_groups.h>
#include <hip/hip_bf16.h>
#include <hip/hip_fp16.h>

namespace cg = cooperative_groups;

// GAT layer, single cooperative mega-kernel (5 phases, grid.sync between),
// ~12.8 MB ws, zero global atomics. Fallback: R19's 5-launch path.
// R20 bug (FIXED): P3 dropped the LDS estage -> in-place regroup raced
// (pass-2 read ebuf while rewriting it). estage restored; races gone.

__device__ __forceinline__ unsigned short f2bf(float f) {
    unsigned u = __float_as_uint(f);
    u += 0x7FFFu + ((u >> 16) & 1u);
    return (unsigned short)(u >> 16);
}
__device__ __forceinline__ float bf2f(unsigned short h) {
    return __uint_as_float(((unsigned)h) << 16);
}

// LDS union arena: P0 needs 26240 B; P3 needs 28224 B (estage 5504 ints).
#define SM_BYTES 28224
#define CAPB_M   5504   // per-bucket stage capacity; data max ~4300 (mean+22sigma)

__global__ __launch_bounds__(256, 4) void k_mega(
    const float* __restrict__ inputs, const int* __restrict__ src,
    const int* __restrict__ dst, const int* __restrict__ ety,
    const float* __restrict__ W1, const float* __restrict__ b1,
    const float* __restrict__ W2, const float* __restrict__ b2,
    const float* __restrict__ edge_emb,
    unsigned short* __restrict__ keys, float* __restrict__ a_src,
    float* __restrict__ a_dst, float* __restrict__ a_ee,
    int* __restrict__ rp, int* __restrict__ histG, int* __restrict__ bsum,
    int* __restrict__ ebuf, __half* __restrict__ wexp, float* __restrict__ dsum,
    float* __restrict__ out, int N, int E, int NB, int ntile, int chunk)
{
    __shared__ __align__(16) char smraw[SM_BYTES];
    cg::grid_group grid = cg::this_grid();
    const int t = threadIdx.x;
    const int blk = blockIdx.x;
    const int nchunks = gridDim.x;

    // ================= P0: GEMM + alphas + histogram =================
    {
        float* W1s  = (float*)smraw;                 // 16384 B
        float* W2s  = (float*)(smraw + 16384);       // 512 B
        float* xs   = (float*)(smraw + 16896);       // 8320 B
        int*  histL = (int*)(smraw + 25216);         // 1024 B

        const float4* W1g = reinterpret_cast<const float4*>(W1);
        float4* W1sv = reinterpret_cast<float4*>(W1s);
#pragma unroll
        for (int i = 0; i < 4; i++) W1sv[t + 256 * i] = W1g[t + 256 * i];
        if (t < 128) W2s[t] = W2[t];

        const int lane = t & 63;
        const int wave = t >> 6;
        const int gidx = wave * 4 + (lane >> 4);
        const int j4   = lane & 15;
        const int rA = 2 * gidx;
        const float4* W1v = reinterpret_cast<const float4*>(W1s);
        const float4 bv4 = reinterpret_cast<const float4*>(b1)[j4];

        for (int tile = blk; tile < ntile; tile += nchunks) {
            const int row0 = tile * 32;
            __syncthreads();
            for (int i = 0; i < 8; i++) {
                int idx = t + 256 * i;
                int r = idx >> 6, c = idx & 63;
                if (row0 + r < N)
                    xs[r * 65 + c] = inputs[(size_t)(row0 + r) * 64 + c];
            }
            __syncthreads();

            float4 acc[2];
            acc[0] = {0.f, 0.f, 0.f, 0.f};
            acc[1] = {0.f, 0.f, 0.f, 0.f};
#pragma unroll 4
            for (int k = 0; k < 64; k++) {
                float4 w = W1v[k * 16 + j4];
                float a0 = xs[rA * 65 + k];
                float a1 = xs[rA * 65 + 65 + k];
                acc[0].x += a0 * w.x; acc[0].y += a0 * w.y;
                acc[0].z += a0 * w.z; acc[0].w += a0 * w.w;
                acc[1].x += a1 * w.x; acc[1].y += a1 * w.y;
                acc[1].z += a1 * w.z; acc[1].w += a1 * w.w;
            }
#pragma unroll
            for (int i = 0; i < 2; i++) {
                int row = row0 + rA + i;
                if (row < N) {
                    float4 a = { acc[i].x + bv4.x, acc[i].y + bv4.y,
                                 acc[i].z + bv4.z, acc[i].w + bv4.w };
                    ushort4 kv;
                    kv.x = f2bf(a.x); kv.y = f2bf(a.y);
                    kv.z = f2bf(a.z); kv.w = f2bf(a.w);
                    reinterpret_cast<ushort4*>(keys)[(size_t)row * 16 + j4] = kv;
                    float p1 = a.x * W2s[4 * j4]     + a.y * W2s[4 * j4 + 1]
                             + a.z * W2s[4 * j4 + 2] + a.w * W2s[4 * j4 + 3];
                    float p2 = a.x * W2s[64 + 4 * j4]     + a.y * W2s[64 + 4 * j4 + 1]
                             + a.z * W2s[64 + 4 * j4 + 2] + a.w * W2s[64 + 4 * j4 + 3];
#pragma unroll
                    for (int m = 8; m >= 1; m >>= 1) {
                        p1 += __shfl_xor(p1, m);
                        p2 += __shfl_xor(p2, m);
                    }
                    if (j4 == 0) { a_src[row] = p1; a_dst[row] = p2; }
                }
            }
        }

        if (blk == 0 && t < 6) {
            float s = 0.f;
            for (int c = 0; c < 64; c++) s += edge_emb[t * 64 + c] * W2s[c];
            a_ee[t] = s;
        }

        __syncthreads();
        for (int b = t; b < NB; b += 256) histL[b] = 0;
        __syncthreads();
        const int lim = min(E, (blk + 1) * chunk);
        for (int e = blk * chunk + t; e < lim; e += 256)
            atomicAdd(&histL[dst[e] >> 8], 1);
        __syncthreads();
        for (int b = t; b < NB; b += 256)
            histG[(size_t)b * nchunks + blk] = histL[b];
    }
    grid.sync();

    // ================= P1: scan each bucket row (nchunks entries) =================
    {
        int* sm = (int*)smraw;
        for (int b = blk; b < NB; b += nchunks) {
            int base = 0;
            for (int c0 = 0; c0 < nchunks; c0 += 1024) {
                int v[4], ssum = 0;
#pragma unroll
                for (int i = 0; i < 4; i++) {
                    int idx = c0 + t * 4 + i;
                    v[i] = (idx < nchunks) ? histG[(size_t)b * nchunks + idx] : 0;
                    ssum += v[i];
                }
                sm[t] = ssum;
                __syncthreads();
                for (int off = 1; off < 256; off <<= 1) {
                    int x = 0;
                    if (t >= off) x = sm[t - off];
                    __syncthreads();
                    if (t >= off) sm[t] += x;
                    __syncthreads();
                }
                int run = base + ((t == 0) ? 0 : sm[t - 1]);
#pragma unroll
                for (int i = 0; i < 4; i++) {
                    int idx = c0 + t * 4 + i;
                    if (idx < nchunks) histG[(size_t)b * nchunks + idx] = run;
                    run += v[i];
                }
                base += sm[255];
                __syncthreads();
            }
            if (t == 0) bsum[b] = base;
        }
    }
    grid.sync();

    // ================= P2: bucket scatter =================
    {
        int* sm  = (int*)smraw;
        int* cur = (int*)(smraw + 1024);
        int bs = (t < NB) ? bsum[t] : 0;
        sm[t] = bs;
        __syncthreads();
        for (int off = 1; off < 256; off <<= 1) {
            int x = 0;
            if (t >= off) x = sm[t - off];
            __syncthreads();
            if (t >= off) sm[t] += x;
            __syncthreads();
        }
        if (t < NB) cur[t] = (sm[t] - bs) + histG[(size_t)t * nchunks + blk];
        __syncthreads();
        const int lim = min(E, (blk + 1) * chunk);
        for (int e = blk * chunk + t; e < lim; e += 256) {
            int d = dst[e];
            int pos = atomicAdd(&cur[d >> 8], 1);
            ebuf[pos] = src[e] | (ety[e] << 16) | ((d & 255) << 19);
        }
    }
    grid.sync();

    // ================= P3: local CSR + exp-once (estage restored: race-free) =====
    {
        int*   boffL = (int*)smraw;                  // 1040 B (257 ints)
        int*   h     = (int*)(smraw + 1040);         // 1024
        int*   sm    = (int*)(smraw + 2064);         // 1024
        int*   cur2  = (int*)(smraw + 3088);         // 1024
        float* fsum  = (float*)(smraw + 4112);       // 1024
        float* baseL = (float*)(smraw + 5136);       // 1024
        float* aeeL  = (float*)(smraw + 6160);       // 48 (8 used)
        int*   estage= (int*)(smraw + 6208);         // 5504 ints = 22016 B

        int bs = (t < NB) ? bsum[t] : 0;
        sm[t] = bs;
        __syncthreads();
        for (int off = 1; off < 256; off <<= 1) {
            int x = 0;
            if (t >= off) x = sm[t - off];
            __syncthreads();
            if (t >= off) sm[t] += x;
            __syncthreads();
        }
        if (t < NB) boffL[t] = sm[t] - bs;           // exclusive
        if (t == NB - 1) boffL[NB] = sm[t];          // = E
        __syncthreads();

        const float b2v = b2[0];
        for (int b = blk; b < NB; b += nchunks) {
            const int begB = boffL[b];
            const int endB = boffL[b + 1];
            const int cnt  = endB - begB;
            const int idx  = (b << 8) + t;

            __syncthreads();
            h[t] = 0;
            fsum[t] = 0.f;
            baseL[t] = (idx < N) ? (a_dst[idx] + b2v) : 0.f;
            if (t < 6) aeeL[t] = a_ee[t];
            __syncthreads();

            for (int i = t; i < cnt; i += 256) {
                int r = ebuf[begB + i];
                if (i < CAPB_M) estage[i] = r;
                atomicAdd(&h[(r >> 19) & 255], 1);
            }
            __syncthreads();

            sm[t] = h[t];
            __syncthreads();
            for (int off = 1; off < 256; off <<= 1) {
                int x = 0;
                if (t >= off) x = sm[t - off];
                __syncthreads();
                if (t >= off) sm[t] += x;
                __syncthreads();
            }
            int lstart = (t == 0) ? 0 : sm[t - 1];
            if (idx < N) rp[idx] = begB + lstart;
            if (b == NB - 1 && t == 0) rp[N] = E;
            cur2[t] = begB + lstart;
            __syncthreads();

            for (int i = t; i < cnt; i += 256) {
                int r = (i < CAPB_M) ? estage[i] : ebuf[begB + i];
                int s  = r & 0xFFFF;
                int ty = (r >> 16) & 7;
                int dl = (r >> 19) & 255;
                float l = a_src[s] + aeeL[ty] + baseL[dl];
                l = fmaxf(0.2f * l, l);
                float w = expf(l);
                int pos = atomicAdd(&cur2[dl], 1);
                ebuf[pos] = r & 0x7FFFF;
                wexp[pos] = __float2half_rn(w);
                atomicAdd(&fsum[dl], w);
            }
            __syncthreads();
            if (idx < N) dsum[idx] = fsum[t];
        }
    }
    grid.sync();

    // ================= P4: output gather =================
    {
        float* ee4 = (float*)smraw;
        int  (*srec)[64] = (int(*)[64])(smraw + 1536);
        float(*sw)[64]   = (float(*)[64])(smraw + 2560);

        __syncthreads();
        for (int i = t; i < 384; i += 256) ee4[i] = edge_emb[i];
        __syncthreads();

        const int lane = t & 63;
        const int wid  = t >> 6;
        const int g    = lane >> 4;
        const int j4   = lane & 15;
        const float4* ee4v = reinterpret_cast<const float4*>(ee4);
        const int nquad = (N + 3) / 4;

        for (int q = blk; q < nquad; q += nchunks) {
            const int d = q * 4 + wid;
            if (d < N) {
                const int beg = rp[d], end = rp[d + 1];
                const float inv = (end > beg) ? 1.f / dsum[d] : 0.f;
                float4 acc0 = {0.f, 0.f, 0.f, 0.f};
                float4 acc1 = {0.f, 0.f, 0.f, 0.f};

                for (int cbase = beg; cbase < end; cbase += 64) {
                    const int n = min(64, end - cbase);
                    if (lane < n) {
                        srec[wid][lane] = ebuf[cbase + lane];
                        sw[wid][lane]   = __half2float(wexp[cbase + lane]);
                    }
                    __builtin_amdgcn_wave_barrier();
                    int j = g;
                    for (; j + 4 < n; j += 8) {
                        int   r0 = srec[wid][j];
                        int   r1 = srec[wid][j + 4];
                        float w0 = sw[wid][j];
                        float w1 = sw[wid][j + 4];
                        int sA = r0 & 0xFFFF, tyA = r0 >> 16;
                        int sB = r1 & 0xFFFF, tyB = r1 >> 16;
                        ushort4 kv0 = reinterpret_cast<const ushort4*>(keys)[(size_t)sA * 16 + j4];
                        ushort4 kv1 = reinterpret_cast<const ushort4*>(keys)[(size_t)sB * 16 + j4];
                        float4  ev0 = ee4v[tyA * 16 + j4];
                        float4  ev1 = ee4v[tyB * 16 + j4];
                        acc0.x += (bf2f(kv0.x) + ev0.x) * w0;
                        acc0.y += (bf2f(kv0.y) + ev0.y) * w0;
                        acc0.z += (bf2f(kv0.z) + ev0.z) * w0;
                        acc0.w += (bf2f(kv0.w) + ev0.w) * w0;
                        acc1.x += (bf2f(kv1.x) + ev1.x) * w1;
                        acc1.y += (bf2f(kv1.y) + ev1.y) * w1;
                        acc1.z += (bf2f(kv1.z) + ev1.z) * w1;
                        acc1.w += (bf2f(kv1.w) + ev1.w) * w1;
                    }
                    if (j < n) {
                        int   r0 = srec[wid][j];
                        float w0 = sw[wid][j];
                        int sA = r0 & 0xFFFF, tyA = r0 >> 16;
                        ushort4 kv0 = reinterpret_cast<const ushort4*>(keys)[(size_t)sA * 16 + j4];
                        float4  ev0 = ee4v[tyA * 16 + j4];
                        acc0.x += (bf2f(kv0.x) + ev0.x) * w0;
                        acc0.y += (bf2f(kv0.y) + ev0.y) * w0;
                        acc0.z += (bf2f(kv0.z) + ev0.z) * w0;
                        acc0.w += (bf2f(kv0.w) + ev0.w) * w0;
                    }
                    __builtin_amdgcn_wave_barrier();
                }

                float4 acc = { acc0.x + acc1.x, acc0.y + acc1.y,
                               acc0.z + acc1.z, acc0.w + acc1.w };
#pragma unroll
                for (int m = 16; m <= 32; m <<= 1) {
                    acc.x += __shfl_xor(acc.x, m);
                    acc.y += __shfl_xor(acc.y, m);
                    acc.z += __shfl_xor(acc.z, m);
                    acc.w += __shfl_xor(acc.w, m);
                }
                if (g == 0) {
                    acc.x *= inv; acc.y *= inv; acc.z *= inv; acc.w *= inv;
                    reinterpret_cast<float4*>(out)[(size_t)d * 16 + j4] = acc;
                }
            }
        }
    }
}

// ---------------- fallback path: R19's proven 5-kernel pipeline ----------------
#define NBLK_H 256
#define CAPB   16384

__global__ __launch_bounds__(256, 4) void k_nodes(
    const float* __restrict__ inputs, const float* __restrict__ W1,
    const float* __restrict__ b1, const float* __restrict__ W2,
    const float* __restrict__ edge_emb, const int* __restrict__ dst,
    unsigned short* __restrict__ keys, float* __restrict__ alpha_src,
    float* __restrict__ alpha_dst, float* __restrict__ alpha_ee,
    int* __restrict__ histG, int N, int E, int NB, int chunk)
{
    __shared__ float W1s[64 * 64];
    __shared__ float W2s[128];
    __shared__ float xs[32 * 65];
    __shared__ int histL[256];

    const int t = threadIdx.x;
    const int row0 = blockIdx.x * 32;

    const float4* W1g = reinterpret_cast<const float4*>(W1);
    float4* W1sv = reinterpret_cast<float4*>(W1s);
#pragma unroll
    for (int i = 0; i < 4; i++) W1sv[t + 256 * i] = W1g[t + 256 * i];
    if (t < 128) W2s[t] = W2[t];

    for (int i = 0; i < 8; i++) {
        int idx = t + 256 * i;
        int r = idx >> 6, c = idx & 63;
        if (row0 + r < N)
            xs[r * 65 + c] = inputs[(size_t)(row0 + r) * 64 + c];
    }
    __syncthreads();

    const int lane = t & 63;
    const int wave = t >> 6;
    const int gidx = wave * 4 + (lane >> 4);
    const int j4   = lane & 15;
    const int rA = 2 * gidx;

    const float4* W1v = reinterpret_cast<const float4*>(W1s);
    float4 acc[2];
    acc[0] = {0.f, 0.f, 0.f, 0.f};
    acc[1] = {0.f, 0.f, 0.f, 0.f};
#pragma unroll 4
    for (int k = 0; k < 64; k++) {
        float4 w = W1v[k * 16 + j4];
        float a0 = xs[rA * 65 + k];
        float a1 = xs[rA * 65 + 65 + k];
        acc[0].x += a0 * w.x; acc[0].y += a0 * w.y;
        acc[0].z += a0 * w.z; acc[0].w += a0 * w.w;
        acc[1].x += a1 * w.x; acc[1].y += a1 * w.y;
        acc[1].z += a1 * w.z; acc[1].w += a1 * w.w;
    }

    const float4 bv = reinterpret_cast<const float4*>(b1)[j4];
#pragma unroll
    for (int i = 0; i < 2; i++) {
        int row = row0 + rA + i;
        if (row < N) {
            float4 a = { acc[i].x + bv.x, acc[i].y + bv.y,
                         acc[i].z + bv.z, acc[i].w + bv.w };
            ushort4 kv;
            kv.x = f2bf(a.x); kv.y = f2bf(a.y); kv.z = f2bf(a.z); kv.w = f2bf(a.w);
            reinterpret_cast<ushort4*>(keys)[(size_t)row * 16 + j4] = kv;
            float p1 = a.x * W2s[4 * j4]     + a.y * W2s[4 * j4 + 1]
                     + a.z * W2s[4 * j4 + 2] + a.w * W2s[4 * j4 + 3];
            float p2 = a.x * W2s[64 + 4 * j4]     + a.y * W2s[64 + 4 * j4 + 1]
                     + a.z * W2s[64 + 4 * j4 + 2] + a.w * W2s[64 + 4 * j4 + 3];
#pragma unroll
            for (int m = 8; m >= 1; m >>= 1) {
                p1 += __shfl_xor(p1, m);
                p2 += __shfl_xor(p2, m);
            }
            if (j4 == 0) { alpha_src[row] = p1; alpha_dst[row] = p2; }
        }
    }

    if (blockIdx.x == 0 && t < 6) {
        float s = 0.f;
        for (int c = 0; c < 64; c++) s += edge_emb[t * 64 + c] * W2s[c];
        alpha_ee[t] = s;
    }

    if (blockIdx.x < NBLK_H) {
        const int blk = blockIdx.x;
        for (int b = t; b < NB; b += 256) histL[b] = 0;
        __syncthreads();
        const int lim = min(E, (blk + 1) * chunk);
        for (int e = blk * chunk + t; e < lim; e += 256)
            atomicAdd(&histL[dst[e] >> 8], 1);
        __syncthreads();
        for (int b = t; b < NB; b += 256)
            histG[b * NBLK_H + blk] = histL[b];
    }
}

__global__ __launch_bounds__(256) void k_scanA(
    int* __restrict__ histG, int* __restrict__ bsum)
{
    __shared__ int sm[256];
    const int t = threadIdx.x;
    const int b = blockIdx.x;
    int v = histG[b * NBLK_H + t];
    sm[t] = v;
    __syncthreads();
    for (int off = 1; off < 256; off <<= 1) {
        int x = 0;
        if (t >= off) x = sm[t - off];
        __syncthreads();
        if (t >= off) sm[t] += x;
        __syncthreads();
    }
    histG[b * NBLK_H + t] = sm[t] - v;
    if (t == 255) bsum[b] = sm[255];
}

__global__ __launch_bounds__(256) void k_bucket_scatter(
    const int* __restrict__ src, const int* __restrict__ dst,
    const int* __restrict__ ety, const int* __restrict__ histG,
    const int* __restrict__ bsum, int* __restrict__ ebuf,
    int E, int NB, int chunk)
{
    __shared__ int sm[256];
    __shared__ int cur[256];
    const int t = threadIdx.x;
    const int blk = blockIdx.x;

    int bs = (t < NB) ? bsum[t] : 0;
    sm[t] = bs;
    __syncthreads();
    for (int off = 1; off < 256; off <<= 1) {
        int x = 0;
        if (t >= off) x = sm[t - off];
        __syncthreads();
        if (t >= off) sm[t] += x;
        __syncthreads();
    }
    if (t < NB) cur[t] = (sm[t] - bs) + histG[t * NBLK_H + blk];
    __syncthreads();

    const int lim = min(E, (blk + 1) * chunk);
    for (int e = blk * chunk + t; e < lim; e += 256) {
        int d = dst[e];
        int pos = atomicAdd(&cur[d >> 8], 1);
        ebuf[pos] = src[e] | (ety[e] << 16) | ((d & 255) << 19);
    }
}

__global__ __launch_bounds__(256) void k_localcsr(
    int* __restrict__ ebuf, const int* __restrict__ bsum,
    const float* __restrict__ a_src, const float* __restrict__ a_dst,
    const float* __restrict__ a_ee, const float* __restrict__ b2,
    int* __restrict__ rp, __half* __restrict__ wexp,
    float* __restrict__ dsum, int N, int NB, int E)
{
    __shared__ int   estage[CAPB];
    __shared__ int   h[256];
    __shared__ int   sm[256];
    __shared__ int   cur2[256];
    __shared__ float fsum[256];
    __shared__ float baseL[256];
    __shared__ float aeeL[8];

    const int t = threadIdx.x;
    const int b = blockIdx.x;
    const int idx = (b << 8) + t;

    int bs = (t < NB) ? bsum[t] : 0;
    sm[t] = bs;
    __syncthreads();
    for (int off = 1; off < 256; off <<= 1) {
        int x = 0;
        if (t >= off) x = sm[t - off];
        __syncthreads();
        if (t >= off) sm[t] += x;
        __syncthreads();
    }
    const int begB = (b == 0) ? 0 : sm[b - 1];
    const int endB = sm[b];
    const int cnt  = endB - begB;
    __syncthreads();

    h[t] = 0;
    fsum[t] = 0.f;
    baseL[t] = (idx < N) ? (a_dst[idx] + b2[0]) : 0.f;
    if (t < 6) aeeL[t] = a_ee[t];
    __syncthreads();

    for (int i = t; i < cnt; i += 256) {
        int r = ebuf[begB + i];
        if (i < CAPB) estage[i] = r;
        atomicAdd(&h[(r >> 19) & 255], 1);
    }
    __syncthreads();

    sm[t] = h[t];
    __syncthreads();
    for (int off = 1; off < 256; off <<= 1) {
        int x = 0;
        if (t >= off) x = sm[t - off];
        __syncthreads();
        if (t >= off) sm[t] += x;
        __syncthreads();
    }
    int lstart = (t == 0) ? 0 : sm[t - 1];

    if (idx < N) rp[idx] = begB + lstart;
    if (b == NB - 1 && t == 0) rp[N] = E;
    cur2[t] = begB + lstart;
    __syncthreads();

    for (int i = t; i < cnt; i += 256) {
        int r = (i < CAPB) ? estage[i] : ebuf[begB + i];
        int s  = r & 0xFFFF;
        int ty = (r >> 16) & 7;
        int dl = (r >> 19) & 255;
        float l = a_src[s] + aeeL[ty] + baseL[dl];
        l = fmaxf(0.2f * l, l);
        float w = expf(l);
        int pos = atomicAdd(&cur2[dl], 1);
        ebuf[pos] = r & 0x7FFFF;
        wexp[pos] = __float2half_rn(w);
        atomicAdd(&fsum[dl], w);
    }
    __syncthreads();
    if (idx < N) dsum[idx] = fsum[t];
}

__global__ __launch_bounds__(256) void k_out(
    const int* __restrict__ rp, const int* __restrict__ erec,
    const __half* __restrict__ wexp, const float* __restrict__ dsum,
    const unsigned short* __restrict__ keys, const float* __restrict__ edge_emb,
    float* __restrict__ out, int N)
{
    __shared__ float ee4[384];
    __shared__ int   srec[4][64];
    __shared__ float sw[4][64];

    const int t = threadIdx.x;
    for (int i = t; i < 384; i += 256) ee4[i] = edge_emb[i];
    __syncthreads();

    const int lane = t & 63;
    const int wid  = t >> 6;
    const int d = blockIdx.x * 4 + wid;
    if (d >= N) return;

    const int beg = rp[d], end = rp[d + 1];
    const float inv = (end > beg) ? 1.f / dsum[d] : 0.f;

    const int g  = lane >> 4;
    const int j4 = lane & 15;
    const float4* ee4v = reinterpret_cast<const float4*>(ee4);
    float4 acc0 = {0.f, 0.f, 0.f, 0.f};
    float4 acc1 = {0.f, 0.f, 0.f, 0.f};

    for (int cbase = beg; cbase < end; cbase += 64) {
        const int n = min(64, end - cbase);
        if (lane < n) {
            srec[wid][lane] = erec[cbase + lane];
            sw[wid][lane]   = __half2float(wexp[cbase + lane]);
        }
        __builtin_amdgcn_wave_barrier();
        int j = g;
        for (; j + 4 < n; j += 8) {
            int   r0 = srec[wid][j];
            int   r1 = srec[wid][j + 4];
            float w0 = sw[wid][j];
            float w1 = sw[wid][j + 4];
            int sA = r0 & 0xFFFF, tyA = r0 >> 16;
            int sB = r1 & 0xFFFF, tyB = r1 >> 16;
            ushort4 kv0 = reinterpret_cast<const ushort4*>(keys)[(size_t)sA * 16 + j4];
            ushort4 kv1 = reinterpret_cast<const ushort4*>(keys)[(size_t)sB * 16 + j4];
            float4  ev0 = ee4v[tyA * 16 + j4];
            float4  ev1 = ee4v[tyB * 16 + j4];
            acc0.x += (bf2f(kv0.x) + ev0.x) * w0;
            acc0.y += (bf2f(kv0.y) + ev0.y) * w0;
            acc0.z += (bf2f(kv0.z) + ev0.z) * w0;
            acc0.w += (bf2f(kv0.w) + ev0.w) * w0;
            acc1.x += (bf2f(kv1.x) + ev1.x) * w1;
            acc1.y += (bf2f(kv1.y) + ev1.y) * w1;
            acc1.z += (bf2f(kv1.z) + ev1.z) * w1;
            acc1.w += (bf2f(kv1.w) + ev1.w) * w1;
        }
        if (j < n) {
            int   r0 = srec[wid][j];
            float w0 = sw[wid][j];
            int sA = r0 & 0xFFFF, tyA = r0 >> 16;
            ushort4 kv0 = reinterpret_cast<const ushort4*>(keys)[(size_t)sA * 16 + j4];
            float4  ev0 = ee4v[tyA * 16 + j4];
            acc0.x += (bf2f(kv0.x) + ev0.x) * w0;
            acc0.y += (bf2f(kv0.y) + ev0.y) * w0;
            acc0.z += (bf2f(kv0.z) + ev0.z) * w0;
            acc0.w += (bf2f(kv0.w) + ev0.w) * w0;
        }
        __builtin_amdgcn_wave_barrier();
    }

    float4 acc = { acc0.x + acc1.x, acc0.y + acc1.y,
                   acc0.z + acc1.z, acc0.w + acc1.w };
#pragma unroll
    for (int m = 16; m <= 32; m <<= 1) {
        acc.x += __shfl_xor(acc.x, m);
        acc.y += __shfl_xor(acc.y, m);
        acc.z += __shfl_xor(acc.z, m);
        acc.w += __shfl_xor(acc.w, m);
    }
    if (g == 0) {
        acc.x *= inv; acc.y *= inv; acc.z *= inv; acc.w *= inv;
        reinterpret_cast<float4*>(out)[(size_t)d * 16 + j4] = acc;
    }
}

extern "C" void kernel_launch(void* const* d_in, const int* in_sizes, int n_in,
                              void* d_out, int out_size, void* d_ws, size_t ws_size,
                              hipStream_t stream) {
    const float* inputs   = (const float*)d_in[0];
    const int*   src      = (const int*)d_in[1];
    const int*   dst      = (const int*)d_in[2];
    const int*   ety      = (const int*)d_in[3];
    const float* W1       = (const float*)d_in[5];
    const float* b1       = (const float*)d_in[6];
    const float* W2       = (const float*)d_in[7];
    const float* b2       = (const float*)d_in[8];
    const float* edge_emb = (const float*)d_in[9];
    float* out = (float*)d_out;

    const int N  = in_sizes[0] / 64;
    const int E  = in_sizes[1];
    const int NB = (N + 255) >> 8;          // 196 buckets of 256 dests
    const int ntile = (N + 31) / 32;

    // cooperative grid sizing (deterministic occupancy query)
    int blocksPerCU = 0;
    hipError_t qerr = hipOccupancyMaxActiveBlocksPerMultiprocessor(
        &blocksPerCU, (const void*)k_mega, 256, 0);
    bool coop_ok = (qerr == hipSuccess && blocksPerCU >= 1);
    int nblk = coop_ok ? blocksPerCU * 256 : 0;
    if (nblk > 2048) nblk = 2048;

    // workspace layout in 4-byte units (histG sized for max grid 2048)
    float*          ws      = (float*)d_ws;
    unsigned short* keys    = (unsigned short*)ws;              // N*32 ints
    float*          a_src   = ws + (size_t)N * 32;              // N
    float*          a_dst   = a_src + N;                        // N
    float*          a_ee    = a_dst + N;                        // 8
    int*            rp      = (int*)(a_ee + 8);                 // N+2
    int*            histG   = rp + (N + 2);                     // NB*2048 max
    int*            bsum    = histG + (size_t)NB * 2048;        // 256
    int*            ebuf    = bsum + 256;                       // E
    __half*         wexp    = (__half*)(ebuf + E);              // E halves
    float*          dsum    = (float*)(wexp + ((E + 1) & ~1));  // N

    if (coop_ok) {
        const int chunk = (E + nblk - 1) / nblk;
        void* args[] = { (void*)&inputs, (void*)&src, (void*)&dst, (void*)&ety,
                         (void*)&W1, (void*)&b1, (void*)&W2, (void*)&b2,
                         (void*)&edge_emb, (void*)&keys, (void*)&a_src,
                         (void*)&a_dst, (void*)&a_ee, (void*)&rp, (void*)&histG,
                         (void*)&bsum, (void*)&ebuf, (void*)&wexp, (void*)&dsum,
                         (void*)&out, (void*)&N, (void*)&E, (void*)&NB,
                         (void*)&ntile, (void*)&chunk };
        hipError_t lerr = hipLaunchCooperativeKernel(
            (const void*)k_mega, dim3(nblk), dim3(256), args, 0, stream);
        if (lerr == hipSuccess) return;
    }

    // fallback: R19's proven 5-launch pipeline
    const int chunkF = (E + NBLK_H - 1) / NBLK_H;
    k_nodes<<<ntile, 256, 0, stream>>>(inputs, W1, b1, W2, edge_emb, dst,
                                       keys, a_src, a_dst, a_ee, histG, N, E, NB, chunkF);
    k_scanA<<<NB, 256, 0, stream>>>(histG, bsum);
    k_bucket_scatter<<<NBLK_H, 256, 0, stream>>>(src, dst, ety, histG,
                                                 bsum, ebuf, E, NB, chunkF);
    k_localcsr<<<NB, 256, 0, stream>>>(ebuf, bsum, a_src, a_dst, a_ee, b2,
                                       rp, wexp, dsum, N, NB, E);
    k_out<<<(N + 3) / 4, 256, 0, stream>>>(rp, ebuf, wexp, dsum, keys, edge_emb, out, N);
}

// Round 22
// 84.024 us; speedup vs baseline: 5.4902x; 5.4902x over previous
//
#include <hip/hip_runtime.h>
#include <hip/hip_bf16.h>

// GAT layer, 16-dest buckets + fused CSR/output, 5 launches, zero global atomics,
// ~12.6 MB ws:
//   keys = inputs @ W1 + b1 (bf16; alphas from f32 acc)
//   logit[e] = leaky(a_src[s]+a_dst[d]+a_ee[ty]+b2); attn = exp/segsum
//   out[d] = sum attn*(keys[s]+ee[ty])
// R21 lesson: grid.sync flushes non-coherent per-XCD L2s (FETCH/WRITE 53/56MB,
// 674us) -> coop path dead. R22: fuse localcsr+k_out per 16-dest bucket so the
// regrouped records/weights never leave LDS (kills ebuf rewrite + wexp + rp).

__device__ __forceinline__ unsigned short f2bf(float f) {
    unsigned u = __float_as_uint(f);
    u += 0x7FFFu + ((u >> 16) & 1u);          // round-nearest-even
    return (unsigned short)(u >> 16);
}
__device__ __forceinline__ float bf2f(unsigned short h) {
    return __uint_as_float(((unsigned)h) << 16);
}

#define NBLK_H 256     // edge chunks for histogram/scatter
#define MAXNB  3200    // LDS capacity for per-bucket arrays (NB = N/16 = 3125)
#define FCAP   1024    // per-bucket edge stage (mean 256, sigma 16 -> 48x sigma)

// GEMM (32 rows/block, 2 rows per 16-lane group) + alphas + fused 3125-bin hist
__global__ __launch_bounds__(256, 4) void k_nodes(
    const float* __restrict__ inputs, const float* __restrict__ W1,
    const float* __restrict__ b1, const float* __restrict__ W2,
    const float* __restrict__ edge_emb, const int* __restrict__ dst,
    unsigned short* __restrict__ keys, float* __restrict__ alpha_src,
    float* __restrict__ alpha_dst, float* __restrict__ alpha_ee,
    int* __restrict__ histG, int N, int E, int NB, int chunk)
{
    __shared__ float W1s[64 * 64];
    __shared__ float W2s[128];
    __shared__ float xs[32 * 65];
    __shared__ int histL[MAXNB];

    const int t = threadIdx.x;
    const int row0 = blockIdx.x * 32;

    const float4* W1g = reinterpret_cast<const float4*>(W1);
    float4* W1sv = reinterpret_cast<float4*>(W1s);
#pragma unroll
    for (int i = 0; i < 4; i++) W1sv[t + 256 * i] = W1g[t + 256 * i];
    if (t < 128) W2s[t] = W2[t];

    for (int i = 0; i < 8; i++) {
        int idx = t + 256 * i;
        int r = idx >> 6, c = idx & 63;
        if (row0 + r < N)
            xs[r * 65 + c] = inputs[(size_t)(row0 + r) * 64 + c];
    }
    __syncthreads();

    const int lane = t & 63;
    const int wave = t >> 6;
    const int gidx = wave * 4 + (lane >> 4);
    const int j4   = lane & 15;
    const int rA = 2 * gidx;

    const float4* W1v = reinterpret_cast<const float4*>(W1s);
    float4 acc[2];
    acc[0] = {0.f, 0.f, 0.f, 0.f};
    acc[1] = {0.f, 0.f, 0.f, 0.f};
#pragma unroll 4
    for (int k = 0; k < 64; k++) {
        float4 w = W1v[k * 16 + j4];
        float a0 = xs[rA * 65 + k];
        float a1 = xs[rA * 65 + 65 + k];
        acc[0].x += a0 * w.x; acc[0].y += a0 * w.y;
        acc[0].z += a0 * w.z; acc[0].w += a0 * w.w;
        acc[1].x += a1 * w.x; acc[1].y += a1 * w.y;
        acc[1].z += a1 * w.z; acc[1].w += a1 * w.w;
    }

    const float4 bv = reinterpret_cast<const float4*>(b1)[j4];
#pragma unroll
    for (int i = 0; i < 2; i++) {
        int row = row0 + rA + i;
        if (row < N) {
            float4 a = { acc[i].x + bv.x, acc[i].y + bv.y,
                         acc[i].z + bv.z, acc[i].w + bv.w };
            ushort4 kv;
            kv.x = f2bf(a.x); kv.y = f2bf(a.y); kv.z = f2bf(a.z); kv.w = f2bf(a.w);
            reinterpret_cast<ushort4*>(keys)[(size_t)row * 16 + j4] = kv;
            float p1 = a.x * W2s[4 * j4]     + a.y * W2s[4 * j4 + 1]
                     + a.z * W2s[4 * j4 + 2] + a.w * W2s[4 * j4 + 3];
            float p2 = a.x * W2s[64 + 4 * j4]     + a.y * W2s[64 + 4 * j4 + 1]
                     + a.z * W2s[64 + 4 * j4 + 2] + a.w * W2s[64 + 4 * j4 + 3];
#pragma unroll
            for (int m = 8; m >= 1; m >>= 1) {
                p1 += __shfl_xor(p1, m);
                p2 += __shfl_xor(p2, m);
            }
            if (j4 == 0) { alpha_src[row] = p1; alpha_dst[row] = p2; }
        }
    }

    if (blockIdx.x == 0 && t < 6) {
        float s = 0.f;
        for (int c = 0; c < 64; c++) s += edge_emb[t * 64 + c] * W2s[c];
        alpha_ee[t] = s;
    }

    // fused histogram (bucket = dst>>4): blockIdx-uniform branch, barriers safe
    if (blockIdx.x < NBLK_H) {
        const int blk = blockIdx.x;
        for (int b = t; b < NB; b += 256) histL[b] = 0;
        __syncthreads();
        const int lim = min(E, (blk + 1) * chunk);
        for (int e = blk * chunk + t; e < lim; e += 256)
            atomicAdd(&histL[dst[e] >> 4], 1);
        __syncthreads();
        for (int b = t; b < NB; b += 256)
            histG[(size_t)b * NBLK_H + blk] = histL[b];
    }
}

// per-bucket row scan: exclusive over 256 chunk-counts, total -> bsum[b]
__global__ __launch_bounds__(256) void k_scanA(
    int* __restrict__ histG, int* __restrict__ bsum)
{
    __shared__ int sm[256];
    const int t = threadIdx.x;
    const size_t b = blockIdx.x;
    int v = histG[b * NBLK_H + t];
    sm[t] = v;
    __syncthreads();
    for (int off = 1; off < 256; off <<= 1) {
        int x = 0;
        if (t >= off) x = sm[t - off];
        __syncthreads();
        if (t >= off) sm[t] += x;
        __syncthreads();
    }
    histG[b * NBLK_H + t] = sm[t] - v;     // exclusive
    if (t == 255) bsum[b] = sm[255];
}

// single-block exclusive scan of bsum[NB] -> boff[0..NB] (boff[NB] = E)
__global__ __launch_bounds__(256) void k_scanB(
    const int* __restrict__ bsum, int* __restrict__ boff, int NB)
{
    __shared__ int sm[256];
    const int t = threadIdx.x;
    const int CH = (NB + 255) / 256;
    int s = 0;
    for (int i = 0; i < CH; i++) {
        int idx = t * CH + i;
        if (idx < NB) s += bsum[idx];
    }
    sm[t] = s;
    __syncthreads();
    for (int off = 1; off < 256; off <<= 1) {
        int x = 0;
        if (t >= off) x = sm[t - off];
        __syncthreads();
        if (t >= off) sm[t] += x;
        __syncthreads();
    }
    int run = (t == 0) ? 0 : sm[t - 1];
    for (int i = 0; i < CH; i++) {
        int idx = t * CH + i;
        if (idx < NB) { boff[idx] = run; run += bsum[idx]; }
    }
    if (t == 255) boff[NB] = sm[255];
}

// scatter into bucket-sorted order; cur = boff + row-scanned histG (LDS cursors)
__global__ __launch_bounds__(256) void k_scatter(
    const int* __restrict__ src, const int* __restrict__ dst,
    const int* __restrict__ ety, const int* __restrict__ histG,
    const int* __restrict__ boff, int* __restrict__ ebuf,
    int E, int NB, int chunk)
{
    __shared__ int cur[MAXNB];
    const int t = threadIdx.x;
    const int blk = blockIdx.x;
    for (int b = t; b < NB; b += 256)
        cur[b] = boff[b] + histG[(size_t)b * NBLK_H + blk];
    __syncthreads();
    const int lim = min(E, (blk + 1) * chunk);
    for (int e = blk * chunk + t; e < lim; e += 256) {
        int d = dst[e];
        int pos = atomicAdd(&cur[d >> 4], 1);
        ebuf[pos] = src[e] | (ety[e] << 16) | ((d & 15) << 19);
    }
}

// one block per 16-dest bucket: stage edges in LDS, 16-bin hist+scan, regroup
// into LDS (srt/sw) computing exp ONCE per edge, then gather-accumulate the 16
// outputs (4 waves x 4 dests, 4x16-lane groups) straight from LDS. No rp/wexp.
__global__ __launch_bounds__(256) void k_fused(
    const int* __restrict__ ebuf, const int* __restrict__ boff,
    const float* __restrict__ a_src, const float* __restrict__ a_dst,
    const float* __restrict__ a_ee, const float* __restrict__ b2,
    const unsigned short* __restrict__ keys, const float* __restrict__ edge_emb,
    float* __restrict__ out, int N)
{
    __shared__ float ee4[384];
    __shared__ int   estage[FCAP];
    __shared__ int   srt[FCAP];
    __shared__ float sw[FCAP];
    __shared__ int   h[16];
    __shared__ int   lstart[17];
    __shared__ int   cur2[16];
    __shared__ float fsumL[16];
    __shared__ float baseL[16];
    __shared__ float aeeL[8];

    const int t = threadIdx.x;
    const int b = blockIdx.x;
    const int d0 = b << 4;
    const int begB = boff[b], endB = boff[b + 1];
    const int cnt = endB - begB;

    for (int i = t; i < 384; i += 256) ee4[i] = edge_emb[i];
    if (t < 16) {
        h[t] = 0;
        fsumL[t] = 0.f;
        baseL[t] = (d0 + t < N) ? (a_dst[d0 + t] + b2[0]) : 0.f;
    }
    if (t < 6) aeeL[t] = a_ee[t];
    __syncthreads();

    // pass A: stage + 16-bin histogram
    for (int i = t; i < cnt; i += 256) {
        int r = ebuf[begB + i];
        if (i < FCAP) estage[i] = r;
        atomicAdd(&h[(r >> 19) & 15], 1);
    }
    __syncthreads();

    if (t == 0) {
        int run = 0;
#pragma unroll
        for (int k = 0; k < 16; k++) { lstart[k] = run; run += h[k]; }
        lstart[16] = run;
    }
    __syncthreads();
    if (t < 16) cur2[t] = lstart[t];
    __syncthreads();

    // pass B: regroup by dest + exp once per edge
    for (int i = t; i < cnt; i += 256) {
        int r = (i < FCAP) ? estage[i] : ebuf[begB + i];
        int s  = r & 0xFFFF;
        int ty = (r >> 16) & 7;
        int dl = (r >> 19) & 15;
        float l = a_src[s] + aeeL[ty] + baseL[dl];
        l = fmaxf(0.2f * l, l);
        float w = expf(l);
        int pos = atomicAdd(&cur2[dl], 1);
        if (pos < FCAP) { srt[pos] = r; sw[pos] = w; }
        atomicAdd(&fsumL[dl], w);
    }
    __syncthreads();

    // gather: wave wid handles dests wid*4 .. wid*4+3; 4x16-lane groups/edge
    const int lane = t & 63;
    const int wid  = t >> 6;
    const int g    = lane >> 4;
    const int j4   = lane & 15;
    const float4* ee4v = reinterpret_cast<const float4*>(ee4);

#pragma unroll
    for (int k = 0; k < 4; k++) {
        const int dl = wid * 4 + k;
        const int d = d0 + dl;
        if (d >= N) continue;
        const int eb = lstart[dl], en = lstart[dl + 1];
        const float inv = (en > eb) ? 1.f / fsumL[dl] : 0.f;
        float4 acc0 = {0.f, 0.f, 0.f, 0.f};
        float4 acc1 = {0.f, 0.f, 0.f, 0.f};

        int j = eb + g;
        for (; j + 4 < en; j += 8) {
            int   r0 = srt[j],  r1 = srt[j + 4];
            float w0 = sw[j],   w1 = sw[j + 4];
            int sA = r0 & 0xFFFF, tyA = (r0 >> 16) & 7;
            int sB = r1 & 0xFFFF, tyB = (r1 >> 16) & 7;
            ushort4 kv0 = reinterpret_cast<const ushort4*>(keys)[(size_t)sA * 16 + j4];
            ushort4 kv1 = reinterpret_cast<const ushort4*>(keys)[(size_t)sB * 16 + j4];
            float4  ev0 = ee4v[tyA * 16 + j4];
            float4  ev1 = ee4v[tyB * 16 + j4];
            acc0.x += (bf2f(kv0.x) + ev0.x) * w0;
            acc0.y += (bf2f(kv0.y) + ev0.y) * w0;
            acc0.z += (bf2f(kv0.z) + ev0.z) * w0;
            acc0.w += (bf2f(kv0.w) + ev0.w) * w0;
            acc1.x += (bf2f(kv1.x) + ev1.x) * w1;
            acc1.y += (bf2f(kv1.y) + ev1.y) * w1;
            acc1.z += (bf2f(kv1.z) + ev1.z) * w1;
            acc1.w += (bf2f(kv1.w) + ev1.w) * w1;
        }
        if (j < en) {
            int   r0 = srt[j];
            float w0 = sw[j];
            int sA = r0 & 0xFFFF, tyA = (r0 >> 16) & 7;
            ushort4 kv0 = reinterpret_cast<const ushort4*>(keys)[(size_t)sA * 16 + j4];
            float4  ev0 = ee4v[tyA * 16 + j4];
            acc0.x += (bf2f(kv0.x) + ev0.x) * w0;
            acc0.y += (bf2f(kv0.y) + ev0.y) * w0;
            acc0.z += (bf2f(kv0.z) + ev0.z) * w0;
            acc0.w += (bf2f(kv0.w) + ev0.w) * w0;
        }

        float4 acc = { acc0.x + acc1.x, acc0.y + acc1.y,
                       acc0.z + acc1.z, acc0.w + acc1.w };
#pragma unroll
        for (int m = 16; m <= 32; m <<= 1) {
            acc.x += __shfl_xor(acc.x, m);
            acc.y += __shfl_xor(acc.y, m);
            acc.z += __shfl_xor(acc.z, m);
            acc.w += __shfl_xor(acc.w, m);
        }
        if (g == 0) {
            acc.x *= inv; acc.y *= inv; acc.z *= inv; acc.w *= inv;
            reinterpret_cast<float4*>(out)[(size_t)d * 16 + j4] = acc;
        }
    }
}

extern "C" void kernel_launch(void* const* d_in, const int* in_sizes, int n_in,
                              void* d_out, int out_size, void* d_ws, size_t ws_size,
                              hipStream_t stream) {
    const float* inputs   = (const float*)d_in[0];
    const int*   src      = (const int*)d_in[1];
    const int*   dst      = (const int*)d_in[2];
    const int*   ety      = (const int*)d_in[3];
    const float* W1       = (const float*)d_in[5];
    const float* b1       = (const float*)d_in[6];
    const float* W2       = (const float*)d_in[7];
    const float* b2       = (const float*)d_in[8];
    const float* edge_emb = (const float*)d_in[9];
    float* out = (float*)d_out;

    const int N  = in_sizes[0] / 64;
    const int E  = in_sizes[1];
    const int NB = (N + 15) >> 4;           // 3125 buckets of 16 dests
    const int chunk = (E + NBLK_H - 1) / NBLK_H;
    const int ntile = (N + 31) / 32;        // 1563 >= 256 (hist chunks)

    // workspace layout in 4-byte units; total ~12.6 MB
    float*          ws      = (float*)d_ws;
    unsigned short* keys    = (unsigned short*)ws;              // N*32 ints
    float*          a_src   = ws + (size_t)N * 32;              // N
    float*          a_dst   = a_src + N;                        // N
    float*          a_ee    = a_dst + N;                        // 8
    int*            histG   = (int*)(a_ee + 8);                 // NB*256
    int*            bsum    = histG + (size_t)NB * NBLK_H;      // NB (pad 3200)
    int*            boff    = bsum + MAXNB;                     // NB+1 (pad 3200)
    int*            ebuf    = boff + MAXNB;                     // E

    k_nodes<<<ntile, 256, 0, stream>>>(inputs, W1, b1, W2, edge_emb, dst,
                                       keys, a_src, a_dst, a_ee, histG, N, E, NB, chunk);
    k_scanA<<<NB, 256, 0, stream>>>(histG, bsum);
    k_scanB<<<1, 256, 0, stream>>>(bsum, boff, NB);
    k_scatter<<<NBLK_H, 256, 0, stream>>>(src, dst, ety, histG, boff, ebuf, E, NB, chunk);
    k_fused<<<NB, 256, 0, stream>>>(ebuf, boff, a_src, a_dst, a_ee, b2,
                                    keys, edge_emb, out, N);
}